// Round 1
// baseline (1093.734 us; speedup 1.0000x reference)
//
#include <hip/hip_runtime.h>
#include <math.h>

#define NN 50000
#define IN_F 50
#define HID 64
#define HEADS 4
#define CH 16
#define NC 12
#define INV_SQRT_C 0.25f
#define LN_EPS 1e-5f

// ---------------- CSR construction ----------------

__global__ void count_kernel(const int* __restrict__ dst, int* __restrict__ cnt, int e) {
  int i = blockIdx.x * blockDim.x + threadIdx.x;
  if (i < e) atomicAdd(&cnt[dst[i]], 1);
}

// single-block chunked exclusive scan: counts -> rowptr[0..n], rowptr[n]=E
__global__ void scan_kernel(const int* __restrict__ cnt, int* __restrict__ rowptr, int n) {
  __shared__ int s[1024];
  int t = threadIdx.x;
  int chunk = (n + 1023) >> 10;
  int begin = t * chunk;
  int end = begin + chunk; if (end > n) end = n;
  int sum = 0;
  for (int i = begin; i < end; i++) sum += cnt[i];
  s[t] = sum;
  __syncthreads();
  for (int off = 1; off < 1024; off <<= 1) {
    int tv = (t >= off) ? s[t - off] : 0;
    __syncthreads();
    if (t >= off) s[t] += tv;
    __syncthreads();
  }
  int run = s[t] - sum;  // exclusive prefix
  for (int i = begin; i < end; i++) { rowptr[i] = run; run += cnt[i]; }
  if (t == 1023) rowptr[n] = s[1023];
}

__global__ void scatter_kernel(const int* __restrict__ src, const int* __restrict__ dst,
                               const float* __restrict__ ea, const int* __restrict__ rowptr,
                               int* __restrict__ fill, int* __restrict__ col,
                               float* __restrict__ eav, int e) {
  int i = blockIdx.x * blockDim.x + threadIdx.x;
  if (i < e) {
    int d = dst[i];
    int pos = atomicAdd(&fill[d], 1);
    int slot = rowptr[d] + pos;
    col[slot] = src[i];
    eav[slot] = ea[i];
  }
}

// ---------------- input GEMM: h = x @ Win + b_in  (N x 50 -> N x 64) ----------------

__global__ __launch_bounds__(256) void ingemm_kernel(const float* __restrict__ x,
    const float* __restrict__ Win, const float* __restrict__ bin,
    float* __restrict__ h, int n) {
  __shared__ float Wsh[IN_F * HID];   // 12.8 KB
  __shared__ float xsh[32][IN_F];     // 6.4 KB
  for (int idx = threadIdx.x; idx < IN_F * HID; idx += 256) Wsh[idx] = Win[idx];
  int wave = threadIdx.x >> 6, lane = threadIdx.x & 63;
  float b = bin[lane];
  int ntiles = (n + 31) / 32;
  for (int tile = blockIdx.x; tile < ntiles; tile += gridDim.x) {
    int row0 = tile * 32;
    __syncthreads();
    for (int idx = threadIdx.x; idx < 32 * IN_F; idx += 256) {
      int r = idx / IN_F, c = idx - r * IN_F;
      if (row0 + r < n) xsh[r][c] = x[(row0 + r) * IN_F + c];
    }
    __syncthreads();
    float acc[8];
#pragma unroll
    for (int r = 0; r < 8; r++) acc[r] = b;
    for (int kx = 0; kx < IN_F; kx++) {
      float w = Wsh[kx * HID + lane];
#pragma unroll
      for (int r = 0; r < 8; r++) acc[r] += xsh[wave * 8 + r][kx] * w;
    }
    int rbase = row0 + wave * 8;
#pragma unroll
    for (int r = 0; r < 8; r++)
      if (rbase + r < n) h[(rbase + r) * HID + lane] = acc[r];
  }
}

// ---------------- fused per-layer GEMM: q,k,v,xr = h @ {Wq,Wk,Wv,Wskip} + bias ----------------
// wave w handles matrix w; 8-row register tile per lane.

__global__ __launch_bounds__(256) void gemm4_kernel(const float* __restrict__ h,
    const float* __restrict__ Wq, const float* __restrict__ bq,
    const float* __restrict__ Wk, const float* __restrict__ bk,
    const float* __restrict__ Wv, const float* __restrict__ bv,
    const float* __restrict__ Ws, const float* __restrict__ bs,
    float* __restrict__ q, float* __restrict__ kk, float* __restrict__ v,
    float* __restrict__ xr, int n) {
  __shared__ float Wsh[4 * HID * HID];  // 64 KB
  __shared__ float hsh[8][HID];         // 2 KB
  for (int idx = threadIdx.x; idx < 4 * HID * HID; idx += 256) {
    int m = idx >> 12, r = idx & 4095;
    const float* Wm = (m == 0) ? Wq : (m == 1) ? Wk : (m == 2) ? Wv : Ws;
    Wsh[idx] = Wm[r];
  }
  int wave = threadIdx.x >> 6, lane = threadIdx.x & 63;
  const float* bm = (wave == 0) ? bq : (wave == 1) ? bk : (wave == 2) ? bv : bs;
  float* om = (wave == 0) ? q : (wave == 1) ? kk : (wave == 2) ? v : xr;
  float bmy = bm[lane];
  const float* Wbase = Wsh + wave * HID * HID;
  int ntiles = (n + 7) / 8;
  for (int tile = blockIdx.x; tile < ntiles; tile += gridDim.x) {
    int row0 = tile * 8;
    __syncthreads();
    for (int idx = threadIdx.x; idx < 8 * HID; idx += 256) {
      int r = idx >> 6, c = idx & 63;
      if (row0 + r < n) hsh[r][c] = h[(row0 + r) * HID + c];
    }
    __syncthreads();
    float acc[8];
#pragma unroll
    for (int r = 0; r < 8; r++) acc[r] = bmy;
#pragma unroll
    for (int kx = 0; kx < HID; kx++) {
      float w = Wbase[kx * HID + lane];
#pragma unroll
      for (int r = 0; r < 8; r++) acc[r] += hsh[r][kx] * w;
    }
#pragma unroll
    for (int r = 0; r < 8; r++)
      if (row0 + r < n) om[(row0 + r) * HID + lane] = acc[r];
  }
}

// ---------------- attention: wave per dst node, online softmax ----------------

__global__ __launch_bounds__(256) void attn_kernel(const int* __restrict__ rowptr,
    const int* __restrict__ col, const float* __restrict__ eav,
    const float* __restrict__ q, const float* __restrict__ k, const float* __restrict__ v,
    const float* __restrict__ wedge, float* __restrict__ outb, int n) {
  int lane = threadIdx.x & 63;
  int node = blockIdx.x * 4 + (threadIdx.x >> 6);
  if (node >= n) return;
  float ql = q[node * HID + lane];
  float wel = wedge[lane];
  int s0 = rowptr[node], s1 = rowptr[node + 1];
  float m = -INFINITY, l = 0.f, acc = 0.f;
  for (int s = s0; s < s1; s++) {
    int srcn = col[s];
    float a = eav[s];
    float el = a * wel;
    float kj = k[srcn * HID + lane] + el;
    float prod = ql * kj;
    prod += __shfl_xor(prod, 1);
    prod += __shfl_xor(prod, 2);
    prod += __shfl_xor(prod, 4);
    prod += __shfl_xor(prod, 8);
    float alpha = prod * INV_SQRT_C;
    float mnew = fmaxf(m, alpha);
    float scale = __expf(m - mnew);   // m=-inf first iter -> 0
    float p = __expf(alpha - mnew);
    l = l * scale + p;
    float vj = v[srcn * HID + lane] + el;
    acc = acc * scale + p * vj;
    m = mnew;
  }
  outb[node * HID + lane] = acc / (l + 1e-16f);
}

// ---------------- gated residual + LayerNorm (in-place on h) ----------------

__global__ __launch_bounds__(256) void post_kernel(const float* __restrict__ outb,
    const float* __restrict__ xr, float* __restrict__ h,
    const float* __restrict__ wbeta, const float* __restrict__ g,
    const float* __restrict__ bb, int n) {
  int lane = threadIdx.x & 63;
  int node = blockIdx.x * 4 + (threadIdx.x >> 6);
  if (node >= n) return;
  float o = outb[node * HID + lane];
  float x = xr[node * HID + lane];
  float hres = h[node * HID + lane];
  float sv = o * wbeta[lane] + x * wbeta[64 + lane] + (o - x) * wbeta[128 + lane];
#pragma unroll
  for (int off = 1; off < 64; off <<= 1) sv += __shfl_xor(sv, off);
  float beta = 1.f / (1.f + __expf(-sv));
  float o2 = beta * x + (1.f - beta) * o;
  float z = o2 + hres;
  float mu = z;
#pragma unroll
  for (int off = 1; off < 64; off <<= 1) mu += __shfl_xor(mu, off);
  mu *= (1.f / 64.f);
  float d = z - mu;
  float var = d * d;
#pragma unroll
  for (int off = 1; off < 64; off <<= 1) var += __shfl_xor(var, off);
  var *= (1.f / 64.f);
  h[node * HID + lane] = d * rsqrtf(var + LN_EPS) * g[lane] + bb[lane];
}

// ---------------- classifier: out = relu(h@Wc1+bc1) @ Wc2 + bc2 ----------------

__global__ __launch_bounds__(256) void cls_kernel(const float* __restrict__ h,
    const float* __restrict__ Wc1, const float* __restrict__ bc1,
    const float* __restrict__ Wc2, const float* __restrict__ bc2,
    float* __restrict__ out, int n) {
  __shared__ float W1[HID * HID];    // 16 KB
  __shared__ float W2[HID * NC];     // 3 KB
  __shared__ float hsh[32][HID];     // 8 KB
  __shared__ float h1sh[4][8][HID + 1];
  for (int idx = threadIdx.x; idx < HID * HID; idx += 256) W1[idx] = Wc1[idx];
  for (int idx = threadIdx.x; idx < HID * NC; idx += 256) W2[idx] = Wc2[idx];
  int wave = threadIdx.x >> 6, lane = threadIdx.x & 63;
  float b1 = bc1[lane];
  int ntiles = (n + 31) / 32;
  for (int tile = blockIdx.x; tile < ntiles; tile += gridDim.x) {
    int row0 = tile * 32;
    __syncthreads();
    for (int idx = threadIdx.x; idx < 32 * HID; idx += 256) {
      int r = idx >> 6, c = idx & 63;
      if (row0 + r < n) hsh[r][c] = h[(row0 + r) * HID + c];
    }
    __syncthreads();
#pragma unroll
    for (int r = 0; r < 8; r++) {
      float acc = b1;
#pragma unroll
      for (int kx = 0; kx < HID; kx++) acc += hsh[wave * 8 + r][kx] * W1[kx * HID + lane];
      h1sh[wave][r][lane] = fmaxf(acc, 0.f);
    }
    // producer/consumer within the same wave via LDS: in-order, compiler inserts waits
    for (int t = lane; t < 8 * NC; t += 64) {
      int r = t / NC, m = t - r * NC;
      float acc = bc2[m];
#pragma unroll
      for (int kx = 0; kx < HID; kx++) acc += h1sh[wave][r][kx] * W2[kx * NC + m];
      int row = row0 + wave * 8 + r;
      if (row < n) out[row * NC + m] = acc;
    }
  }
}

// ---------------- launch ----------------

extern "C" void kernel_launch(void* const* d_in, const int* in_sizes, int n_in,
                              void* d_out, int out_size, void* d_ws, size_t ws_size,
                              hipStream_t stream) {
  const float* x     = (const float*)d_in[0];
  const int*   eidx  = (const int*)d_in[1];
  const float* eattr = (const float*)d_in[2];
  const float* Win   = (const float*)d_in[3];
  const float* b_in  = (const float*)d_in[4];
  const float* Wq    = (const float*)d_in[5];
  const float* bq    = (const float*)d_in[6];
  const float* Wk    = (const float*)d_in[7];
  const float* bk    = (const float*)d_in[8];
  const float* Wv    = (const float*)d_in[9];
  const float* bv    = (const float*)d_in[10];
  const float* Wedge = (const float*)d_in[11];
  const float* Wskip = (const float*)d_in[12];
  const float* bskip = (const float*)d_in[13];
  const float* Wbeta = (const float*)d_in[14];
  const float* ln_g  = (const float*)d_in[15];
  const float* ln_b  = (const float*)d_in[16];
  const float* Wc1   = (const float*)d_in[17];
  const float* bc1   = (const float*)d_in[18];
  const float* Wc2   = (const float*)d_in[19];
  const float* bc2   = (const float*)d_in[20];
  float* out = (float*)d_out;

  int n = in_sizes[0] / IN_F;   // 50000
  int e = in_sizes[2];          // 800000
  const int* src = eidx;
  const int* dstp = eidx + e;

  char* ws = (char*)d_ws;
  size_t off = 0;
  auto alloc = [&](size_t bytes) { void* p = ws + off; off += (bytes + 255) & ~(size_t)255; return p; };
  int*   rowptr = (int*)alloc((size_t)(n + 1) * 4);
  int*   fill   = (int*)alloc((size_t)n * 4);
  int*   col    = (int*)alloc((size_t)e * 4);
  float* eav    = (float*)alloc((size_t)e * 4);
  float* h      = (float*)alloc((size_t)n * HID * 4);
  float* qb     = (float*)alloc((size_t)n * HID * 4);
  float* kb     = (float*)alloc((size_t)n * HID * 4);
  float* vb     = (float*)alloc((size_t)n * HID * 4);
  float* xrb    = (float*)alloc((size_t)n * HID * 4);
  float* outb   = (float*)alloc((size_t)n * HID * 4);

  hipMemsetAsync(fill, 0, (size_t)n * 4, stream);
  count_kernel<<<(e + 255) / 256, 256, 0, stream>>>(dstp, fill, e);
  scan_kernel<<<1, 1024, 0, stream>>>(fill, rowptr, n);
  hipMemsetAsync(fill, 0, (size_t)n * 4, stream);
  scatter_kernel<<<(e + 255) / 256, 256, 0, stream>>>(src, dstp, eattr, rowptr, fill, col, eav, e);

  ingemm_kernel<<<(n + 31) / 32, 256, 0, stream>>>(x, Win, b_in, h, n);

  for (int i = 0; i < 3; i++) {
    gemm4_kernel<<<1536, 256, 0, stream>>>(h,
        Wq + i * HID * HID, bq + i * HID,
        Wk + i * HID * HID, bk + i * HID,
        Wv + i * HID * HID, bv + i * HID,
        Wskip + i * HID * HID, bskip + i * HID,
        qb, kb, vb, xrb, n);
    attn_kernel<<<(n + 3) / 4, 256, 0, stream>>>(rowptr, col, eav, qb, kb, vb,
        Wedge + i * HID, outb, n);
    post_kernel<<<(n + 3) / 4, 256, 0, stream>>>(outb, xrb, h,
        Wbeta + i * 3 * HID, ln_g + i * HID, ln_b + i * HID, n);
  }

  cls_kernel<<<1024, 256, 0, stream>>>(h, Wc1, bc1, Wc2, bc2, out, n);
}

// Round 2
// 606.014 us; speedup vs baseline: 1.8048x; 1.8048x over previous
//
#include <hip/hip_runtime.h>
#include <math.h>

#define IN_F 50
#define HID 64
#define NC 12
#define LN_EPS 1e-5f

// ---------------- CSR construction ----------------

__global__ void count_kernel(const int* __restrict__ dst, int* __restrict__ cnt, int e) {
  int i = blockIdx.x * blockDim.x + threadIdx.x;
  if (i < e) atomicAdd(&cnt[dst[i]], 1);
}

__global__ void scan_kernel(const int* __restrict__ cnt, int* __restrict__ rowptr, int n) {
  __shared__ int s[1024];
  int t = threadIdx.x;
  int chunk = (n + 1023) >> 10;
  int begin = t * chunk;
  int end = begin + chunk; if (end > n) end = n;
  int sum = 0;
  for (int i = begin; i < end; i++) sum += cnt[i];
  s[t] = sum;
  __syncthreads();
  for (int off = 1; off < 1024; off <<= 1) {
    int tv = (t >= off) ? s[t - off] : 0;
    __syncthreads();
    if (t >= off) s[t] += tv;
    __syncthreads();
  }
  int run = s[t] - sum;
  for (int i = begin; i < end; i++) { rowptr[i] = run; run += cnt[i]; }
  if (t == 1023) rowptr[n] = s[1023];
}

__global__ void scatter_kernel(const int* __restrict__ src, const int* __restrict__ dst,
                               const float* __restrict__ ea, const int* __restrict__ rowptr,
                               int* __restrict__ fill, int* __restrict__ col,
                               float* __restrict__ eav, int e) {
  int i = blockIdx.x * blockDim.x + threadIdx.x;
  if (i < e) {
    int d = dst[i];
    int pos = atomicAdd(&fill[d], 1);
    int slot = rowptr[d] + pos;
    col[slot] = src[i];
    eav[slot] = ea[i];
  }
}

// ---------------- generic tiled GEMM: C[M][*] = A[M][K] @ B[K][NCG*64] + bias ----------------
// Block: 256 threads = 16 row-groups (ty) x 16 col-groups (tx); thread tile 4 rows x (NCG*4) cols.
// Per k: 1 A b128 (broadcast, 4 addrs/wave) + NCG B b128 (stride 4 floats -> 2-way alias, free)
// vs 16*NCG FMA -> VALU-bound. grid.y selects which pair of 64-col matrices.

template<int K, int NCG, bool RELU>
__global__ __launch_bounds__(256, 3) void gemm_tiled(
    const float* __restrict__ A, int lda, int M,
    const float* __restrict__ B0, const float* __restrict__ B1,
    const float* __restrict__ B2, const float* __restrict__ B3,
    const float* __restrict__ g0, const float* __restrict__ g1,
    const float* __restrict__ g2, const float* __restrict__ g3,
    float* __restrict__ C, int ldc)
{
  constexpr int NT = NCG * 64;
  __shared__ __align__(16) float Ash[K * 68];   // A^T: Ash[k*68 + row]
  __shared__ __align__(16) float Bsh[K * NT];
  __shared__ float bsh[NT];
  const int tid = threadIdx.x;
  const int row0 = blockIdx.x * 64;
  // stage A (coalesced reads; staging writes have minor bank aliasing - one-time)
  for (int i = tid; i < 64 * K; i += 256) {
    int r = i / K, k = i - r * K;
    int gr = row0 + r;
    Ash[k * 68 + r] = (gr < M) ? A[gr * lda + k] : 0.f;
  }
#pragma unroll
  for (int g = 0; g < NCG; g++) {
    int cg = blockIdx.y * NCG + g;
    const float* Bp = (cg == 0) ? B0 : (cg == 1) ? B1 : (cg == 2) ? B2 : B3;
    const float* bp = (cg == 0) ? g0 : (cg == 1) ? g1 : (cg == 2) ? g2 : g3;
    for (int i = tid; i < 64 * K; i += 256) {
      int k = i >> 6, c = i & 63;
      Bsh[k * NT + g * 64 + c] = Bp[k * 64 + c];
    }
    if (tid < 64) bsh[g * 64 + tid] = bp[tid];
  }
  __syncthreads();
  const int ty = tid >> 4, tx = tid & 15;
  float acc[4][NCG * 4];
#pragma unroll
  for (int i = 0; i < 4; i++)
#pragma unroll
    for (int g = 0; g < NCG; g++)
#pragma unroll
      for (int c = 0; c < 4; c++)
        acc[i][g * 4 + c] = bsh[g * 64 + tx * 4 + c];
#pragma unroll 4
  for (int k = 0; k < K; k++) {
    float4 av = *(const float4*)&Ash[k * 68 + ty * 4];
    float a_[4] = {av.x, av.y, av.z, av.w};
    float b_[NCG][4];
#pragma unroll
    for (int g = 0; g < NCG; g++) {
      float4 bv = *(const float4*)&Bsh[k * NT + g * 64 + tx * 4];
      b_[g][0] = bv.x; b_[g][1] = bv.y; b_[g][2] = bv.z; b_[g][3] = bv.w;
    }
#pragma unroll
    for (int i = 0; i < 4; i++)
#pragma unroll
      for (int g = 0; g < NCG; g++)
#pragma unroll
        for (int c = 0; c < 4; c++)
          acc[i][g * 4 + c] = fmaf(a_[i], b_[g][c], acc[i][g * 4 + c]);
  }
#pragma unroll
  for (int i = 0; i < 4; i++) {
    int r = row0 + ty * 4 + i;
    if (r < M) {
#pragma unroll
      for (int g = 0; g < NCG; g++) {
        float4 ov;
        ov.x = acc[i][g * 4 + 0]; ov.y = acc[i][g * 4 + 1];
        ov.z = acc[i][g * 4 + 2]; ov.w = acc[i][g * 4 + 3];
        if (RELU) {
          ov.x = fmaxf(ov.x, 0.f); ov.y = fmaxf(ov.y, 0.f);
          ov.z = fmaxf(ov.z, 0.f); ov.w = fmaxf(ov.w, 0.f);
        }
        *(float4*)&C[(size_t)r * ldc + (blockIdx.y * NCG + g) * 64 + tx * 4] = ov;
      }
    }
  }
}

// ---------------- fused attention + gate + LayerNorm ----------------
// qkvx layout: [node][256] = q(0:64) | k(64:128) | v(128:192) | xr(192:256)
// Wave per dst node. lane = grp*16 + c4: grp = edge slot (4 edges/iter), c4 = channel quad.

__global__ __launch_bounds__(256) void attn_post_kernel(
    const int* __restrict__ rowptr, const int* __restrict__ col,
    const float* __restrict__ eav, const float* __restrict__ qkvx,
    const float* __restrict__ wedge, const float* __restrict__ wbeta,
    const float* __restrict__ lng, const float* __restrict__ lnb,
    float* __restrict__ h, int n)
{
  int lane = threadIdx.x & 63;
  int node = blockIdx.x * 4 + (threadIdx.x >> 6);
  if (node >= n) return;
  int grp = lane >> 4;
  int c4 = lane & 15;
  const float4* row4 = (const float4*)qkvx;   // 64 float4 per node row
  float4 q4 = row4[(size_t)node * 64 + c4];
  float4 we4 = ((const float4*)wedge)[c4];
  int s0 = rowptr[node], s1 = rowptr[node + 1];
  float m = -INFINITY, l = 0.f;
  float ax = 0.f, ay = 0.f, az = 0.f, aw = 0.f;
  for (int s = s0; s < s1; s += 4) {
    int es = s + grp;
    bool valid = es < s1;
    int srcn = valid ? col[es] : 0;
    float a = valid ? eav[es] : 0.f;
    float ex = a * we4.x, ey = a * we4.y, ez = a * we4.z, ew = a * we4.w;
    const float4* sb = row4 + (size_t)srcn * 64;
    float4 k4 = sb[16 + c4];
    float4 v4 = sb[32 + c4];
    float prod = q4.x * (k4.x + ex) + q4.y * (k4.y + ey)
               + q4.z * (k4.z + ez) + q4.w * (k4.w + ew);
    prod += __shfl_xor(prod, 1);
    prod += __shfl_xor(prod, 2);            // per-head 16-chan dot
    float alpha = valid ? prod * 0.25f : -INFINITY;
    float am = alpha;
    am = fmaxf(am, __shfl_xor(am, 16));
    am = fmaxf(am, __shfl_xor(am, 32));     // max over 4 edge slots
    float mnew = fmaxf(m, am);
    float msafe = (mnew == -INFINITY) ? 0.f : mnew;
    float scale = __expf(m - msafe);        // first iter: exp(-inf)=0
    float p = __expf(alpha - msafe);        // masked: 0
    float ps = p;
    ps += __shfl_xor(ps, 16);
    ps += __shfl_xor(ps, 32);
    l = l * scale + ps;
    ax = ax * scale + p * (v4.x + ex);
    ay = ay * scale + p * (v4.y + ey);
    az = az * scale + p * (v4.z + ez);
    aw = aw * scale + p * (v4.w + ew);
    m = mnew;
  }
  // sum partial accumulators across the 4 edge-slot groups (result in all lanes)
  ax += __shfl_xor(ax, 16); ax += __shfl_xor(ax, 32);
  ay += __shfl_xor(ay, 16); ay += __shfl_xor(ay, 32);
  az += __shfl_xor(az, 16); az += __shfl_xor(az, 32);
  aw += __shfl_xor(aw, 16); aw += __shfl_xor(aw, 32);
  float inv = 1.f / (l + 1e-16f);
  float ox = ax * inv, oy = ay * inv, oz = az * inv, ow = aw * inv;
  // ---- gate + LN (all 4 groups compute identically; group 0 writes) ----
  float4 xr = row4[(size_t)node * 64 + 48 + c4];
  float4 hr = ((const float4*)h)[(size_t)node * 16 + c4];
  float4 w1 = ((const float4*)wbeta)[c4];
  float4 w2 = ((const float4*)wbeta)[16 + c4];
  float4 w3 = ((const float4*)wbeta)[32 + c4];
  float sv = ox * w1.x + oy * w1.y + oz * w1.z + ow * w1.w
           + xr.x * w2.x + xr.y * w2.y + xr.z * w2.z + xr.w * w2.w
           + (ox - xr.x) * w3.x + (oy - xr.y) * w3.y
           + (oz - xr.z) * w3.z + (ow - xr.w) * w3.w;
  sv += __shfl_xor(sv, 1); sv += __shfl_xor(sv, 2);
  sv += __shfl_xor(sv, 4); sv += __shfl_xor(sv, 8);
  float beta = 1.f / (1.f + __expf(-sv));
  float zx = beta * xr.x + (1.f - beta) * ox + hr.x;
  float zy = beta * xr.y + (1.f - beta) * oy + hr.y;
  float zz = beta * xr.z + (1.f - beta) * oz + hr.z;
  float zw = beta * xr.w + (1.f - beta) * ow + hr.w;
  float mu = zx + zy + zz + zw;
  mu += __shfl_xor(mu, 1); mu += __shfl_xor(mu, 2);
  mu += __shfl_xor(mu, 4); mu += __shfl_xor(mu, 8);
  mu *= (1.f / 64.f);
  float dx = zx - mu, dy = zy - mu, dz = zz - mu, dw = zw - mu;
  float var = dx * dx + dy * dy + dz * dz + dw * dw;
  var += __shfl_xor(var, 1); var += __shfl_xor(var, 2);
  var += __shfl_xor(var, 4); var += __shfl_xor(var, 8);
  var *= (1.f / 64.f);
  float rstd = rsqrtf(var + LN_EPS);
  float4 g4 = ((const float4*)lng)[c4];
  float4 b4 = ((const float4*)lnb)[c4];
  if (grp == 0) {
    float4 res;
    res.x = dx * rstd * g4.x + b4.x;
    res.y = dy * rstd * g4.y + b4.y;
    res.z = dz * rstd * g4.z + b4.z;
    res.w = dw * rstd * g4.w + b4.w;
    ((float4*)h)[(size_t)node * 16 + c4] = res;
  }
}

// ---------------- classifier stage 2: out = h1 @ Wc2 + bc2 ----------------

__global__ __launch_bounds__(256) void cls2_kernel(const float* __restrict__ h1,
    const float* __restrict__ Wc2, const float* __restrict__ bc2,
    float* __restrict__ out, int n) {
  __shared__ float W2[HID * NC];
  __shared__ float b2[NC];
  int tid = threadIdx.x;
  for (int i = tid; i < HID * NC; i += 256) W2[i] = Wc2[i];
  if (tid < NC) b2[tid] = bc2[tid];
  __syncthreads();
  int row = blockIdx.x * 256 + tid;
  if (row >= n) return;
  float a[NC];
#pragma unroll
  for (int mm = 0; mm < NC; mm++) a[mm] = b2[mm];
  const float4* hp = (const float4*)(h1 + (size_t)row * HID);
#pragma unroll
  for (int k4 = 0; k4 < 16; k4++) {
    float4 hv = hp[k4];
    float h_[4] = {hv.x, hv.y, hv.z, hv.w};
#pragma unroll
    for (int kk = 0; kk < 4; kk++)
#pragma unroll
      for (int mm = 0; mm < NC; mm++)
        a[mm] = fmaf(h_[kk], W2[(k4 * 4 + kk) * NC + mm], a[mm]);
  }
#pragma unroll
  for (int mm = 0; mm < NC; mm++) out[(size_t)row * NC + mm] = a[mm];
}

// ---------------- launch ----------------

extern "C" void kernel_launch(void* const* d_in, const int* in_sizes, int n_in,
                              void* d_out, int out_size, void* d_ws, size_t ws_size,
                              hipStream_t stream) {
  const float* x     = (const float*)d_in[0];
  const int*   eidx  = (const int*)d_in[1];
  const float* eattr = (const float*)d_in[2];
  const float* Win   = (const float*)d_in[3];
  const float* b_in  = (const float*)d_in[4];
  const float* Wq    = (const float*)d_in[5];
  const float* bq    = (const float*)d_in[6];
  const float* Wk    = (const float*)d_in[7];
  const float* bk    = (const float*)d_in[8];
  const float* Wv    = (const float*)d_in[9];
  const float* bv    = (const float*)d_in[10];
  const float* Wedge = (const float*)d_in[11];
  const float* Wskip = (const float*)d_in[12];
  const float* bskip = (const float*)d_in[13];
  const float* Wbeta = (const float*)d_in[14];
  const float* ln_g  = (const float*)d_in[15];
  const float* ln_b  = (const float*)d_in[16];
  const float* Wc1   = (const float*)d_in[17];
  const float* bc1   = (const float*)d_in[18];
  const float* Wc2   = (const float*)d_in[19];
  const float* bc2   = (const float*)d_in[20];
  float* out = (float*)d_out;

  int n = in_sizes[0] / IN_F;   // 50000
  int e = in_sizes[2];          // 800000
  const int* src = eidx;
  const int* dstp = eidx + e;

  char* ws = (char*)d_ws;
  size_t off = 0;
  auto alloc = [&](size_t bytes) { void* p = ws + off; off += (bytes + 255) & ~(size_t)255; return p; };
  int*   rowptr = (int*)alloc((size_t)(n + 1) * 4);
  int*   fill   = (int*)alloc((size_t)n * 4);
  int*   col    = (int*)alloc((size_t)e * 4);
  float* eav    = (float*)alloc((size_t)e * 4);
  float* h      = (float*)alloc((size_t)n * HID * 4);
  float* qkvx   = (float*)alloc((size_t)n * 256 * 4);
  float* h1     = (float*)alloc((size_t)n * HID * 4);

  hipMemsetAsync(fill, 0, (size_t)n * 4, stream);
  count_kernel<<<(e + 255) / 256, 256, 0, stream>>>(dstp, fill, e);
  scan_kernel<<<1, 1024, 0, stream>>>(fill, rowptr, n);
  hipMemsetAsync(fill, 0, (size_t)n * 4, stream);
  scatter_kernel<<<(e + 255) / 256, 256, 0, stream>>>(src, dstp, eattr, rowptr, fill, col, eav, e);

  int mtiles = (n + 63) / 64;   // 782
  // h = x @ Win + b_in
  gemm_tiled<IN_F, 1, false><<<dim3(mtiles, 1), 256, 0, stream>>>(
      x, IN_F, n, Win, Win, Win, Win, b_in, b_in, b_in, b_in, h, HID);

  for (int i = 0; i < 3; i++) {
    gemm_tiled<HID, 2, false><<<dim3(mtiles, 2), 256, 0, stream>>>(
        h, HID, n,
        Wq + i * HID * HID, Wk + i * HID * HID, Wv + i * HID * HID, Wskip + i * HID * HID,
        bq + i * HID, bk + i * HID, bv + i * HID, bskip + i * HID,
        qkvx, 256);
    attn_post_kernel<<<(n + 3) / 4, 256, 0, stream>>>(
        rowptr, col, eav, qkvx, Wedge + i * HID, Wbeta + i * 3 * HID,
        ln_g + i * HID, ln_b + i * HID, h, n);
  }

  gemm_tiled<HID, 1, true><<<dim3(mtiles, 1), 256, 0, stream>>>(
      h, HID, n, Wc1, Wc1, Wc1, Wc1, bc1, bc1, bc1, bc1, h1, HID);
  cls2_kernel<<<(n + 255) / 256, 256, 0, stream>>>(h1, Wc2, bc2, out, n);
}

// Round 3
// 535.148 us; speedup vs baseline: 2.0438x; 1.1324x over previous
//
#include <hip/hip_runtime.h>
#include <math.h>

#define IN_F 50
#define HID 64
#define NC 12
#define LN_EPS 1e-5f

// ---------------- CSR construction ----------------

__global__ void count_kernel(const int* __restrict__ dst, int* __restrict__ cnt, int e) {
  int i = blockIdx.x * blockDim.x + threadIdx.x;
  if (i < e) atomicAdd(&cnt[dst[i]], 1);
}

// ---- 3-phase exclusive scan over n counts (chunk = 1024 per block) ----

__global__ __launch_bounds__(256) void scan_reduce_kernel(const int* __restrict__ cnt,
                                                          int* __restrict__ part, int n) {
  int base = blockIdx.x * 1024;
  int sum = 0;
  for (int i = threadIdx.x; i < 1024; i += 256) {
    int g = base + i;
    if (g < n) sum += cnt[g];
  }
#pragma unroll
  for (int off = 1; off < 64; off <<= 1) sum += __shfl_xor(sum, off);
  __shared__ int ws[4];
  if ((threadIdx.x & 63) == 0) ws[threadIdx.x >> 6] = sum;
  __syncthreads();
  if (threadIdx.x == 0) part[blockIdx.x] = ws[0] + ws[1] + ws[2] + ws[3];
}

// one wave scans up to 64 partials; writes exclusive partials + grand total
__global__ void scan_part_kernel(int* __restrict__ part, int nb, int* __restrict__ total) {
  int lane = threadIdx.x;
  int orig = (lane < nb) ? part[lane] : 0;
  int v = orig;
#pragma unroll
  for (int off = 1; off < 64; off <<= 1) {
    int t = __shfl_up(v, off);
    if (lane >= off) v += t;
  }
  if (lane < nb) part[lane] = v - orig;   // exclusive
  if (lane == 63) *total = v;             // rowptr[n]
}

__global__ __launch_bounds__(256) void scan_apply_kernel(const int* __restrict__ cnt,
    const int* __restrict__ part, int* __restrict__ rowptr, int n) {
  int base = blockIdx.x * 1024;
  int t = threadIdx.x;
  int vals[4];
  int lsum = 0;
#pragma unroll
  for (int j = 0; j < 4; j++) {
    int g = base + t * 4 + j;
    vals[j] = (g < n) ? cnt[g] : 0;
    lsum += vals[j];
  }
  int v = lsum;
#pragma unroll
  for (int off = 1; off < 64; off <<= 1) {
    int tv = __shfl_up(v, off);
    if ((t & 63) >= off) v += tv;
  }
  __shared__ int wsum[4];
  if ((t & 63) == 63) wsum[t >> 6] = v;
  __syncthreads();
  int wbase = 0;
  int w = t >> 6;
#pragma unroll
  for (int j = 0; j < 4; j++) if (j < w) wbase += wsum[j];
  int excl = v - lsum + wbase + part[blockIdx.x];
#pragma unroll
  for (int j = 0; j < 4; j++) {
    int g = base + t * 4 + j;
    if (g < n) rowptr[g] = excl;
    excl += vals[j];
  }
}

// scatter: consumes fill (holds counts) by atomic decrement -> no second memset
__global__ void scatter_kernel(const int* __restrict__ src, const int* __restrict__ dst,
                               const float* __restrict__ ea, const int* __restrict__ rowptr,
                               int* __restrict__ fill, int* __restrict__ col,
                               float* __restrict__ eav, int e) {
  int i = blockIdx.x * blockDim.x + threadIdx.x;
  if (i < e) {
    int d = dst[i];
    int pos = atomicSub(&fill[d], 1) - 1;   // cnt-1 .. 0 (order irrelevant)
    int slot = rowptr[d] + pos;
    col[slot] = src[i];
    eav[slot] = ea[i];
  }
}

// ---------------- generic tiled GEMM: C[M][*] = A[M][K] @ B[K][NCG*64] + bias ----------------

template<int K, int NCG, bool RELU>
__global__ __launch_bounds__(256, 3) void gemm_tiled(
    const float* __restrict__ A, int lda, int M,
    const float* __restrict__ B0, const float* __restrict__ B1,
    const float* __restrict__ B2, const float* __restrict__ B3,
    const float* __restrict__ g0, const float* __restrict__ g1,
    const float* __restrict__ g2, const float* __restrict__ g3,
    float* __restrict__ C, int ldc)
{
  constexpr int NT = NCG * 64;
  __shared__ __align__(16) float Ash[K * 68];   // A^T: Ash[k*68 + row]
  __shared__ __align__(16) float Bsh[K * NT];
  __shared__ float bsh[NT];
  const int tid = threadIdx.x;
  const int row0 = blockIdx.x * 64;
  for (int i = tid; i < 64 * K; i += 256) {
    int r = i / K, k = i - r * K;
    int gr = row0 + r;
    Ash[k * 68 + r] = (gr < M) ? A[gr * lda + k] : 0.f;
  }
#pragma unroll
  for (int g = 0; g < NCG; g++) {
    int cg = blockIdx.y * NCG + g;
    const float* Bp = (cg == 0) ? B0 : (cg == 1) ? B1 : (cg == 2) ? B2 : B3;
    const float* bp = (cg == 0) ? g0 : (cg == 1) ? g1 : (cg == 2) ? g2 : g3;
    for (int i = tid; i < 64 * K; i += 256) {
      int k = i >> 6, c = i & 63;
      Bsh[k * NT + g * 64 + c] = Bp[k * 64 + c];
    }
    if (tid < 64) bsh[g * 64 + tid] = bp[tid];
  }
  __syncthreads();
  const int ty = tid >> 4, tx = tid & 15;
  float acc[4][NCG * 4];
#pragma unroll
  for (int i = 0; i < 4; i++)
#pragma unroll
    for (int g = 0; g < NCG; g++)
#pragma unroll
      for (int c = 0; c < 4; c++)
        acc[i][g * 4 + c] = bsh[g * 64 + tx * 4 + c];
#pragma unroll 4
  for (int k = 0; k < K; k++) {
    float4 av = *(const float4*)&Ash[k * 68 + ty * 4];
    float a_[4] = {av.x, av.y, av.z, av.w};
    float b_[NCG][4];
#pragma unroll
    for (int g = 0; g < NCG; g++) {
      float4 bv = *(const float4*)&Bsh[k * NT + g * 64 + tx * 4];
      b_[g][0] = bv.x; b_[g][1] = bv.y; b_[g][2] = bv.z; b_[g][3] = bv.w;
    }
#pragma unroll
    for (int i = 0; i < 4; i++)
#pragma unroll
      for (int g = 0; g < NCG; g++)
#pragma unroll
        for (int c = 0; c < 4; c++)
          acc[i][g * 4 + c] = fmaf(a_[i], b_[g][c], acc[i][g * 4 + c]);
  }
#pragma unroll
  for (int i = 0; i < 4; i++) {
    int r = row0 + ty * 4 + i;
    if (r < M) {
#pragma unroll
      for (int g = 0; g < NCG; g++) {
        float4 ov;
        ov.x = acc[i][g * 4 + 0]; ov.y = acc[i][g * 4 + 1];
        ov.z = acc[i][g * 4 + 2]; ov.w = acc[i][g * 4 + 3];
        if (RELU) {
          ov.x = fmaxf(ov.x, 0.f); ov.y = fmaxf(ov.y, 0.f);
          ov.z = fmaxf(ov.z, 0.f); ov.w = fmaxf(ov.w, 0.f);
        }
        *(float4*)&C[(size_t)r * ldc + (blockIdx.y * NCG + g) * 64 + tx * 4] = ov;
      }
    }
  }
}

// ---------------- fused attention + gate + LayerNorm ----------------
// qkvx layout: [node][256] = q(0:64) | k(64:128) | v(128:192) | xr(192:256)

__global__ __launch_bounds__(256) void attn_post_kernel(
    const int* __restrict__ rowptr, const int* __restrict__ col,
    const float* __restrict__ eav, const float* __restrict__ qkvx,
    const float* __restrict__ wedge, const float* __restrict__ wbeta,
    const float* __restrict__ lng, const float* __restrict__ lnb,
    float* __restrict__ h, int n)
{
  int lane = threadIdx.x & 63;
  int node = blockIdx.x * 4 + (threadIdx.x >> 6);
  if (node >= n) return;
  int grp = lane >> 4;
  int c4 = lane & 15;
  const float4* row4 = (const float4*)qkvx;   // 64 float4 per node row
  float4 q4 = row4[(size_t)node * 64 + c4];
  float4 we4 = ((const float4*)wedge)[c4];
  int s0 = rowptr[node], s1 = rowptr[node + 1];
  float m = -INFINITY, l = 0.f;
  float ax = 0.f, ay = 0.f, az = 0.f, aw = 0.f;
  for (int s = s0; s < s1; s += 4) {
    int es = s + grp;
    bool valid = es < s1;
    int srcn = valid ? col[es] : 0;
    float a = valid ? eav[es] : 0.f;
    float ex = a * we4.x, ey = a * we4.y, ez = a * we4.z, ew = a * we4.w;
    const float4* sb = row4 + (size_t)srcn * 64;
    float4 k4 = sb[16 + c4];
    float4 v4 = sb[32 + c4];
    float prod = q4.x * (k4.x + ex) + q4.y * (k4.y + ey)
               + q4.z * (k4.z + ez) + q4.w * (k4.w + ew);
    prod += __shfl_xor(prod, 1);
    prod += __shfl_xor(prod, 2);            // per-head 16-chan dot
    float alpha = valid ? prod * 0.25f : -INFINITY;
    float am = alpha;
    am = fmaxf(am, __shfl_xor(am, 16));
    am = fmaxf(am, __shfl_xor(am, 32));     // max over 4 edge slots
    float mnew = fmaxf(m, am);
    float msafe = (mnew == -INFINITY) ? 0.f : mnew;
    float scale = __expf(m - msafe);
    float p = __expf(alpha - msafe);
    float ps = p;
    ps += __shfl_xor(ps, 16);
    ps += __shfl_xor(ps, 32);
    l = l * scale + ps;
    ax = ax * scale + p * (v4.x + ex);
    ay = ay * scale + p * (v4.y + ey);
    az = az * scale + p * (v4.z + ez);
    aw = aw * scale + p * (v4.w + ew);
    m = mnew;
  }
  ax += __shfl_xor(ax, 16); ax += __shfl_xor(ax, 32);
  ay += __shfl_xor(ay, 16); ay += __shfl_xor(ay, 32);
  az += __shfl_xor(az, 16); az += __shfl_xor(az, 32);
  aw += __shfl_xor(aw, 16); aw += __shfl_xor(aw, 32);
  float inv = 1.f / (l + 1e-16f);
  float ox = ax * inv, oy = ay * inv, oz = az * inv, ow = aw * inv;
  float4 xr = row4[(size_t)node * 64 + 48 + c4];
  float4 hr = ((const float4*)h)[(size_t)node * 16 + c4];
  float4 w1 = ((const float4*)wbeta)[c4];
  float4 w2 = ((const float4*)wbeta)[16 + c4];
  float4 w3 = ((const float4*)wbeta)[32 + c4];
  float sv = ox * w1.x + oy * w1.y + oz * w1.z + ow * w1.w
           + xr.x * w2.x + xr.y * w2.y + xr.z * w2.z + xr.w * w2.w
           + (ox - xr.x) * w3.x + (oy - xr.y) * w3.y
           + (oz - xr.z) * w3.z + (ow - xr.w) * w3.w;
  sv += __shfl_xor(sv, 1); sv += __shfl_xor(sv, 2);
  sv += __shfl_xor(sv, 4); sv += __shfl_xor(sv, 8);
  float beta = 1.f / (1.f + __expf(-sv));
  float zx = beta * xr.x + (1.f - beta) * ox + hr.x;
  float zy = beta * xr.y + (1.f - beta) * oy + hr.y;
  float zz = beta * xr.z + (1.f - beta) * oz + hr.z;
  float zw = beta * xr.w + (1.f - beta) * ow + hr.w;
  float mu = zx + zy + zz + zw;
  mu += __shfl_xor(mu, 1); mu += __shfl_xor(mu, 2);
  mu += __shfl_xor(mu, 4); mu += __shfl_xor(mu, 8);
  mu *= (1.f / 64.f);
  float dx = zx - mu, dy = zy - mu, dz = zz - mu, dw = zw - mu;
  float var = dx * dx + dy * dy + dz * dz + dw * dw;
  var += __shfl_xor(var, 1); var += __shfl_xor(var, 2);
  var += __shfl_xor(var, 4); var += __shfl_xor(var, 8);
  var *= (1.f / 64.f);
  float rstd = rsqrtf(var + LN_EPS);
  float4 g4 = ((const float4*)lng)[c4];
  float4 b4 = ((const float4*)lnb)[c4];
  if (grp == 0) {
    float4 res;
    res.x = dx * rstd * g4.x + b4.x;
    res.y = dy * rstd * g4.y + b4.y;
    res.z = dz * rstd * g4.z + b4.z;
    res.w = dw * rstd * g4.w + b4.w;
    ((float4*)h)[(size_t)node * 16 + c4] = res;
  }
}

// ---------------- classifier stage 2: out = h1 @ Wc2 + bc2 ----------------

__global__ __launch_bounds__(256) void cls2_kernel(const float* __restrict__ h1,
    const float* __restrict__ Wc2, const float* __restrict__ bc2,
    float* __restrict__ out, int n) {
  __shared__ float W2[HID * NC];
  __shared__ float b2[NC];
  int tid = threadIdx.x;
  for (int i = tid; i < HID * NC; i += 256) W2[i] = Wc2[i];
  if (tid < NC) b2[tid] = bc2[tid];
  __syncthreads();
  int row = blockIdx.x * 256 + tid;
  if (row >= n) return;
  float a[NC];
#pragma unroll
  for (int mm = 0; mm < NC; mm++) a[mm] = b2[mm];
  const float4* hp = (const float4*)(h1 + (size_t)row * HID);
#pragma unroll
  for (int k4 = 0; k4 < 16; k4++) {
    float4 hv = hp[k4];
    float h_[4] = {hv.x, hv.y, hv.z, hv.w};
#pragma unroll
    for (int kk = 0; kk < 4; kk++)
#pragma unroll
      for (int mm = 0; mm < NC; mm++)
        a[mm] = fmaf(h_[kk], W2[(k4 * 4 + kk) * NC + mm], a[mm]);
  }
#pragma unroll
  for (int mm = 0; mm < NC; mm++) out[(size_t)row * NC + mm] = a[mm];
}

// ---------------- launch ----------------

extern "C" void kernel_launch(void* const* d_in, const int* in_sizes, int n_in,
                              void* d_out, int out_size, void* d_ws, size_t ws_size,
                              hipStream_t stream) {
  const float* x     = (const float*)d_in[0];
  const int*   eidx  = (const int*)d_in[1];
  const float* eattr = (const float*)d_in[2];
  const float* Win   = (const float*)d_in[3];
  const float* b_in  = (const float*)d_in[4];
  const float* Wq    = (const float*)d_in[5];
  const float* bq    = (const float*)d_in[6];
  const float* Wk    = (const float*)d_in[7];
  const float* bk    = (const float*)d_in[8];
  const float* Wv    = (const float*)d_in[9];
  const float* bv    = (const float*)d_in[10];
  const float* Wedge = (const float*)d_in[11];
  const float* Wskip = (const float*)d_in[12];
  const float* bskip = (const float*)d_in[13];
  const float* Wbeta = (const float*)d_in[14];
  const float* ln_g  = (const float*)d_in[15];
  const float* ln_b  = (const float*)d_in[16];
  const float* Wc1   = (const float*)d_in[17];
  const float* bc1   = (const float*)d_in[18];
  const float* Wc2   = (const float*)d_in[19];
  const float* bc2   = (const float*)d_in[20];
  float* out = (float*)d_out;

  int n = in_sizes[0] / IN_F;   // 50000
  int e = in_sizes[2];          // 800000
  const int* src = eidx;
  const int* dstp = eidx + e;

  char* ws = (char*)d_ws;
  size_t off = 0;
  auto alloc = [&](size_t bytes) { void* p = ws + off; off += (bytes + 255) & ~(size_t)255; return p; };
  int*   rowptr = (int*)alloc((size_t)(n + 1) * 4);
  int*   fill   = (int*)alloc((size_t)n * 4);
  int*   part   = (int*)alloc(64 * 4);
  int*   col    = (int*)alloc((size_t)e * 4);
  float* eav    = (float*)alloc((size_t)e * 4);
  float* h      = (float*)alloc((size_t)n * HID * 4);
  float* qkvx   = (float*)alloc((size_t)n * 256 * 4);
  float* h1     = (float*)alloc((size_t)n * HID * 4);

  int nb = (n + 1023) / 1024;   // 49 (fits in one wave's scan)

  hipMemsetAsync(fill, 0, (size_t)n * 4, stream);
  count_kernel<<<(e + 255) / 256, 256, 0, stream>>>(dstp, fill, e);
  scan_reduce_kernel<<<nb, 256, 0, stream>>>(fill, part, n);
  scan_part_kernel<<<1, 64, 0, stream>>>(part, nb, rowptr + n);
  scan_apply_kernel<<<nb, 256, 0, stream>>>(fill, part, rowptr, n);
  scatter_kernel<<<(e + 255) / 256, 256, 0, stream>>>(src, dstp, eattr, rowptr, fill, col, eav, e);

  int mtiles = (n + 63) / 64;   // 782
  gemm_tiled<IN_F, 1, false><<<dim3(mtiles, 1), 256, 0, stream>>>(
      x, IN_F, n, Win, Win, Win, Win, b_in, b_in, b_in, b_in, h, HID);

  for (int i = 0; i < 3; i++) {
    gemm_tiled<HID, 2, false><<<dim3(mtiles, 2), 256, 0, stream>>>(
        h, HID, n,
        Wq + i * HID * HID, Wk + i * HID * HID, Wv + i * HID * HID, Wskip + i * HID * HID,
        bq + i * HID, bk + i * HID, bv + i * HID, bskip + i * HID,
        qkvx, 256);
    attn_post_kernel<<<(n + 3) / 4, 256, 0, stream>>>(
        rowptr, col, eav, qkvx, Wedge + i * HID, Wbeta + i * 3 * HID,
        ln_g + i * HID, ln_b + i * HID, h, n);
  }

  gemm_tiled<HID, 1, true><<<dim3(mtiles, 1), 256, 0, stream>>>(
      h, HID, n, Wc1, Wc1, Wc1, Wc1, bc1, bc1, bc1, bc1, h1, HID);
  cls2_kernel<<<(n + 255) / 256, 256, 0, stream>>>(h1, Wc2, bc2, out, n);
}

// Round 4
// 499.786 us; speedup vs baseline: 2.1884x; 1.0708x over previous
//
#include <hip/hip_runtime.h>
#include <hip/hip_fp16.h>
#include <math.h>

#define IN_F 50
#define HID 64
#define NC 12
#define LN_EPS 1e-5f

// ---------------- CSR construction ----------------

__global__ void count_kernel(const int* __restrict__ dst, int* __restrict__ cnt, int e) {
  int i = blockIdx.x * blockDim.x + threadIdx.x;
  if (i < e) atomicAdd(&cnt[dst[i]], 1);
}

// ---- 3-phase exclusive scan over n counts (chunk = 1024 per block) ----

__global__ __launch_bounds__(256) void scan_reduce_kernel(const int* __restrict__ cnt,
                                                          int* __restrict__ part, int n) {
  int base = blockIdx.x * 1024;
  int sum = 0;
  for (int i = threadIdx.x; i < 1024; i += 256) {
    int g = base + i;
    if (g < n) sum += cnt[g];
  }
#pragma unroll
  for (int off = 1; off < 64; off <<= 1) sum += __shfl_xor(sum, off);
  __shared__ int ws[4];
  if ((threadIdx.x & 63) == 0) ws[threadIdx.x >> 6] = sum;
  __syncthreads();
  if (threadIdx.x == 0) part[blockIdx.x] = ws[0] + ws[1] + ws[2] + ws[3];
}

__global__ void scan_part_kernel(int* __restrict__ part, int nb, int* __restrict__ total) {
  int lane = threadIdx.x;
  int orig = (lane < nb) ? part[lane] : 0;
  int v = orig;
#pragma unroll
  for (int off = 1; off < 64; off <<= 1) {
    int t = __shfl_up(v, off);
    if (lane >= off) v += t;
  }
  if (lane < nb) part[lane] = v - orig;   // exclusive
  if (lane == 63) *total = v;             // rowptr[n]
}

__global__ __launch_bounds__(256) void scan_apply_kernel(const int* __restrict__ cnt,
    const int* __restrict__ part, int* __restrict__ rowptr, int n) {
  int base = blockIdx.x * 1024;
  int t = threadIdx.x;
  int vals[4];
  int lsum = 0;
#pragma unroll
  for (int j = 0; j < 4; j++) {
    int g = base + t * 4 + j;
    vals[j] = (g < n) ? cnt[g] : 0;
    lsum += vals[j];
  }
  int v = lsum;
#pragma unroll
  for (int off = 1; off < 64; off <<= 1) {
    int tv = __shfl_up(v, off);
    if ((t & 63) >= off) v += tv;
  }
  __shared__ int wsum[4];
  if ((t & 63) == 63) wsum[t >> 6] = v;
  __syncthreads();
  int wbase = 0;
  int w = t >> 6;
#pragma unroll
  for (int j = 0; j < 4; j++) if (j < w) wbase += wsum[j];
  int excl = v - lsum + wbase + part[blockIdx.x];
#pragma unroll
  for (int j = 0; j < 4; j++) {
    int g = base + t * 4 + j;
    if (g < n) rowptr[g] = excl;
    excl += vals[j];
  }
}

__global__ void scatter_kernel(const int* __restrict__ src, const int* __restrict__ dst,
                               const float* __restrict__ ea, const int* __restrict__ rowptr,
                               int* __restrict__ fill, int* __restrict__ col,
                               float* __restrict__ eav, int e) {
  int i = blockIdx.x * blockDim.x + threadIdx.x;
  if (i < e) {
    int d = dst[i];
    int pos = atomicSub(&fill[d], 1) - 1;   // cnt-1 .. 0 (order irrelevant)
    int slot = rowptr[d] + pos;
    col[slot] = src[i];
    eav[slot] = ea[i];
  }
}

// ---------------- generic tiled GEMM: C[M][*] = A[M][K] @ B[K][NCG*64] + bias ----------------
// WKV: cg==1 (k) and cg==2 (v) are written as fp16 into the interleaved gather
// buffer kvb[node][c4][k4|v4] instead of fp32 C (nothing reads fp32 k/v).

template<int K, int NCG, bool RELU, bool WKV>
__global__ __launch_bounds__(256, 3) void gemm_tiled(
    const float* __restrict__ A, int lda, int M,
    const float* __restrict__ B0, const float* __restrict__ B1,
    const float* __restrict__ B2, const float* __restrict__ B3,
    const float* __restrict__ g0, const float* __restrict__ g1,
    const float* __restrict__ g2, const float* __restrict__ g3,
    float* __restrict__ C, int ldc, __half* __restrict__ kvb)
{
  constexpr int NT = NCG * 64;
  __shared__ __align__(16) float Ash[K * 68];   // A^T: Ash[k*68 + row]
  __shared__ __align__(16) float Bsh[K * NT];
  __shared__ float bsh[NT];
  const int tid = threadIdx.x;
  const int row0 = blockIdx.x * 64;
  for (int i = tid; i < 64 * K; i += 256) {
    int r = i / K, k = i - r * K;
    int gr = row0 + r;
    Ash[k * 68 + r] = (gr < M) ? A[gr * lda + k] : 0.f;
  }
#pragma unroll
  for (int g = 0; g < NCG; g++) {
    int cg = blockIdx.y * NCG + g;
    const float* Bp = (cg == 0) ? B0 : (cg == 1) ? B1 : (cg == 2) ? B2 : B3;
    const float* bp = (cg == 0) ? g0 : (cg == 1) ? g1 : (cg == 2) ? g2 : g3;
    for (int i = tid; i < 64 * K; i += 256) {
      int k = i >> 6, c = i & 63;
      Bsh[k * NT + g * 64 + c] = Bp[k * 64 + c];
    }
    if (tid < 64) bsh[g * 64 + tid] = bp[tid];
  }
  __syncthreads();
  const int ty = tid >> 4, tx = tid & 15;
  float acc[4][NCG * 4];
#pragma unroll
  for (int i = 0; i < 4; i++)
#pragma unroll
    for (int g = 0; g < NCG; g++)
#pragma unroll
      for (int c = 0; c < 4; c++)
        acc[i][g * 4 + c] = bsh[g * 64 + tx * 4 + c];
#pragma unroll 4
  for (int k = 0; k < K; k++) {
    float4 av = *(const float4*)&Ash[k * 68 + ty * 4];
    float a_[4] = {av.x, av.y, av.z, av.w};
    float b_[NCG][4];
#pragma unroll
    for (int g = 0; g < NCG; g++) {
      float4 bv = *(const float4*)&Bsh[k * NT + g * 64 + tx * 4];
      b_[g][0] = bv.x; b_[g][1] = bv.y; b_[g][2] = bv.z; b_[g][3] = bv.w;
    }
#pragma unroll
    for (int i = 0; i < 4; i++)
#pragma unroll
      for (int g = 0; g < NCG; g++)
#pragma unroll
        for (int c = 0; c < 4; c++)
          acc[i][g * 4 + c] = fmaf(a_[i], b_[g][c], acc[i][g * 4 + c]);
  }
#pragma unroll
  for (int i = 0; i < 4; i++) {
    int r = row0 + ty * 4 + i;
    if (r < M) {
#pragma unroll
      for (int g = 0; g < NCG; g++) {
        int cg = blockIdx.y * NCG + g;
        if (WKV && (cg == 1 || cg == 2)) {
          // fp16 interleaved gather buffer: [node][tx][k4(8B) v4(8B)]
          __half hv[4];
#pragma unroll
          for (int c = 0; c < 4; c++) hv[c] = __float2half(acc[i][g * 4 + c]);
          *(ushort4*)&kvb[(size_t)r * 128 + tx * 8 + ((cg == 1) ? 0 : 4)] =
              *(ushort4*)hv;
        } else {
          float4 ov;
          ov.x = acc[i][g * 4 + 0]; ov.y = acc[i][g * 4 + 1];
          ov.z = acc[i][g * 4 + 2]; ov.w = acc[i][g * 4 + 3];
          if (RELU) {
            ov.x = fmaxf(ov.x, 0.f); ov.y = fmaxf(ov.y, 0.f);
            ov.z = fmaxf(ov.z, 0.f); ov.w = fmaxf(ov.w, 0.f);
          }
          *(float4*)&C[(size_t)r * ldc + cg * 64 + tx * 4] = ov;
        }
      }
    }
  }
}

// ---------------- fused attention + gate + LayerNorm ----------------
// qkvx layout: [node][256] = q(0:64) | unused | unused | xr(192:256)
// kvb layout:  [node][16 uint4]: lane c4 -> {k[c4*4..+3], v[c4*4..+3]} fp16

__global__ __launch_bounds__(256) void attn_post_kernel(
    const int* __restrict__ rowptr, const int* __restrict__ col,
    const float* __restrict__ eav, const float* __restrict__ qkvx,
    const uint4* __restrict__ kvb,
    const float* __restrict__ wedge, const float* __restrict__ wbeta,
    const float* __restrict__ lng, const float* __restrict__ lnb,
    float* __restrict__ h, int n)
{
  int lane = threadIdx.x & 63;
  int node = blockIdx.x * 4 + (threadIdx.x >> 6);
  if (node >= n) return;
  int grp = lane >> 4;
  int c4 = lane & 15;
  const float4* row4 = (const float4*)qkvx;   // 64 float4 per node row
  float4 q4 = row4[(size_t)node * 64 + c4];
  float4 we4 = ((const float4*)wedge)[c4];
  int s0 = rowptr[node], s1 = rowptr[node + 1];
  float m = -INFINITY, l = 0.f;
  float ax = 0.f, ay = 0.f, az = 0.f, aw = 0.f;
  for (int s = s0; s < s1; s += 4) {
    int es = s + grp;
    bool valid = es < s1;
    int srcn = valid ? col[es] : 0;
    float a = valid ? eav[es] : 0.f;
    float ex = a * we4.x, ey = a * we4.y, ez = a * we4.z, ew = a * we4.w;
    uint4 kv = kvb[(size_t)srcn * 16 + c4];          // one dwordx4 per edge
    float2 k01 = __half22float2(*(__half2*)&kv.x);
    float2 k23 = __half22float2(*(__half2*)&kv.y);
    float2 v01 = __half22float2(*(__half2*)&kv.z);
    float2 v23 = __half22float2(*(__half2*)&kv.w);
    float prod = q4.x * (k01.x + ex) + q4.y * (k01.y + ey)
               + q4.z * (k23.x + ez) + q4.w * (k23.y + ew);
    prod += __shfl_xor(prod, 1);
    prod += __shfl_xor(prod, 2);            // per-head 16-chan dot
    float alpha = valid ? prod * 0.25f : -INFINITY;
    float am = alpha;
    am = fmaxf(am, __shfl_xor(am, 16));
    am = fmaxf(am, __shfl_xor(am, 32));     // max over 4 edge slots
    float mnew = fmaxf(m, am);
    float msafe = (mnew == -INFINITY) ? 0.f : mnew;
    float scale = __expf(m - msafe);
    float p = __expf(alpha - msafe);
    float ps = p;
    ps += __shfl_xor(ps, 16);
    ps += __shfl_xor(ps, 32);
    l = l * scale + ps;
    ax = ax * scale + p * (v01.x + ex);
    ay = ay * scale + p * (v01.y + ey);
    az = az * scale + p * (v23.x + ez);
    aw = aw * scale + p * (v23.y + ew);
    m = mnew;
  }
  ax += __shfl_xor(ax, 16); ax += __shfl_xor(ax, 32);
  ay += __shfl_xor(ay, 16); ay += __shfl_xor(ay, 32);
  az += __shfl_xor(az, 16); az += __shfl_xor(az, 32);
  aw += __shfl_xor(aw, 16); aw += __shfl_xor(aw, 32);
  float inv = 1.f / (l + 1e-16f);
  float ox = ax * inv, oy = ay * inv, oz = az * inv, ow = aw * inv;
  float4 xr = row4[(size_t)node * 64 + 48 + c4];
  float4 hr = ((const float4*)h)[(size_t)node * 16 + c4];
  float4 w1 = ((const float4*)wbeta)[c4];
  float4 w2 = ((const float4*)wbeta)[16 + c4];
  float4 w3 = ((const float4*)wbeta)[32 + c4];
  float sv = ox * w1.x + oy * w1.y + oz * w1.z + ow * w1.w
           + xr.x * w2.x + xr.y * w2.y + xr.z * w2.z + xr.w * w2.w
           + (ox - xr.x) * w3.x + (oy - xr.y) * w3.y
           + (oz - xr.z) * w3.z + (ow - xr.w) * w3.w;
  sv += __shfl_xor(sv, 1); sv += __shfl_xor(sv, 2);
  sv += __shfl_xor(sv, 4); sv += __shfl_xor(sv, 8);
  float beta = 1.f / (1.f + __expf(-sv));
  float zx = beta * xr.x + (1.f - beta) * ox + hr.x;
  float zy = beta * xr.y + (1.f - beta) * oy + hr.y;
  float zz = beta * xr.z + (1.f - beta) * oz + hr.z;
  float zw = beta * xr.w + (1.f - beta) * ow + hr.w;
  float mu = zx + zy + zz + zw;
  mu += __shfl_xor(mu, 1); mu += __shfl_xor(mu, 2);
  mu += __shfl_xor(mu, 4); mu += __shfl_xor(mu, 8);
  mu *= (1.f / 64.f);
  float dx = zx - mu, dy = zy - mu, dz = zz - mu, dw = zw - mu;
  float var = dx * dx + dy * dy + dz * dz + dw * dw;
  var += __shfl_xor(var, 1); var += __shfl_xor(var, 2);
  var += __shfl_xor(var, 4); var += __shfl_xor(var, 8);
  var *= (1.f / 64.f);
  float rstd = rsqrtf(var + LN_EPS);
  float4 g4 = ((const float4*)lng)[c4];
  float4 b4 = ((const float4*)lnb)[c4];
  if (grp == 0) {
    float4 res;
    res.x = dx * rstd * g4.x + b4.x;
    res.y = dy * rstd * g4.y + b4.y;
    res.z = dz * rstd * g4.z + b4.z;
    res.w = dw * rstd * g4.w + b4.w;
    ((float4*)h)[(size_t)node * 16 + c4] = res;
  }
}

// ---------------- classifier stage 2: out = h1 @ Wc2 + bc2 ----------------

__global__ __launch_bounds__(256) void cls2_kernel(const float* __restrict__ h1,
    const float* __restrict__ Wc2, const float* __restrict__ bc2,
    float* __restrict__ out, int n) {
  __shared__ float W2[HID * NC];
  __shared__ float b2[NC];
  int tid = threadIdx.x;
  for (int i = tid; i < HID * NC; i += 256) W2[i] = Wc2[i];
  if (tid < NC) b2[tid] = bc2[tid];
  __syncthreads();
  int row = blockIdx.x * 256 + tid;
  if (row >= n) return;
  float a[NC];
#pragma unroll
  for (int mm = 0; mm < NC; mm++) a[mm] = b2[mm];
  const float4* hp = (const float4*)(h1 + (size_t)row * HID);
#pragma unroll
  for (int k4 = 0; k4 < 16; k4++) {
    float4 hv = hp[k4];
    float h_[4] = {hv.x, hv.y, hv.z, hv.w};
#pragma unroll
    for (int kk = 0; kk < 4; kk++)
#pragma unroll
      for (int mm = 0; mm < NC; mm++)
        a[mm] = fmaf(h_[kk], W2[(k4 * 4 + kk) * NC + mm], a[mm]);
  }
#pragma unroll
  for (int mm = 0; mm < NC; mm++) out[(size_t)row * NC + mm] = a[mm];
}

// ---------------- launch ----------------

extern "C" void kernel_launch(void* const* d_in, const int* in_sizes, int n_in,
                              void* d_out, int out_size, void* d_ws, size_t ws_size,
                              hipStream_t stream) {
  const float* x     = (const float*)d_in[0];
  const int*   eidx  = (const int*)d_in[1];
  const float* eattr = (const float*)d_in[2];
  const float* Win   = (const float*)d_in[3];
  const float* b_in  = (const float*)d_in[4];
  const float* Wq    = (const float*)d_in[5];
  const float* bq    = (const float*)d_in[6];
  const float* Wk    = (const float*)d_in[7];
  const float* bk    = (const float*)d_in[8];
  const float* Wv    = (const float*)d_in[9];
  const float* bv    = (const float*)d_in[10];
  const float* Wedge = (const float*)d_in[11];
  const float* Wskip = (const float*)d_in[12];
  const float* bskip = (const float*)d_in[13];
  const float* Wbeta = (const float*)d_in[14];
  const float* ln_g  = (const float*)d_in[15];
  const float* ln_b  = (const float*)d_in[16];
  const float* Wc1   = (const float*)d_in[17];
  const float* bc1   = (const float*)d_in[18];
  const float* Wc2   = (const float*)d_in[19];
  const float* bc2   = (const float*)d_in[20];
  float* out = (float*)d_out;

  int n = in_sizes[0] / IN_F;   // 50000
  int e = in_sizes[2];          // 800000
  const int* src = eidx;
  const int* dstp = eidx + e;

  char* ws = (char*)d_ws;
  size_t off = 0;
  auto alloc = [&](size_t bytes) { void* p = ws + off; off += (bytes + 255) & ~(size_t)255; return p; };
  int*    rowptr = (int*)alloc((size_t)(n + 1) * 4);
  int*    fill   = (int*)alloc((size_t)n * 4);
  int*    part   = (int*)alloc(64 * 4);
  int*    col    = (int*)alloc((size_t)e * 4);
  float*  eav    = (float*)alloc((size_t)e * 4);
  float*  h      = (float*)alloc((size_t)n * HID * 4);
  float*  qkvx   = (float*)alloc((size_t)n * 256 * 4);
  __half* kvb    = (__half*)alloc((size_t)n * 128 * 2);
  float*  h1     = (float*)alloc((size_t)n * HID * 4);

  int nb = (n + 1023) / 1024;   // 49 (fits in one wave's scan)

  hipMemsetAsync(fill, 0, (size_t)n * 4, stream);
  count_kernel<<<(e + 255) / 256, 256, 0, stream>>>(dstp, fill, e);
  scan_reduce_kernel<<<nb, 256, 0, stream>>>(fill, part, n);
  scan_part_kernel<<<1, 64, 0, stream>>>(part, nb, rowptr + n);
  scan_apply_kernel<<<nb, 256, 0, stream>>>(fill, part, rowptr, n);
  scatter_kernel<<<(e + 255) / 256, 256, 0, stream>>>(src, dstp, eattr, rowptr, fill, col, eav, e);

  int mtiles = (n + 63) / 64;   // 782
  gemm_tiled<IN_F, 1, false, false><<<dim3(mtiles, 1), 256, 0, stream>>>(
      x, IN_F, n, Win, Win, Win, Win, b_in, b_in, b_in, b_in, h, HID, nullptr);

  for (int i = 0; i < 3; i++) {
    gemm_tiled<HID, 2, false, true><<<dim3(mtiles, 2), 256, 0, stream>>>(
        h, HID, n,
        Wq + i * HID * HID, Wk + i * HID * HID, Wv + i * HID * HID, Wskip + i * HID * HID,
        bq + i * HID, bk + i * HID, bv + i * HID, bskip + i * HID,
        qkvx, 256, kvb);
    attn_post_kernel<<<(n + 3) / 4, 256, 0, stream>>>(
        rowptr, col, eav, qkvx, (const uint4*)kvb, Wedge + i * HID, Wbeta + i * 3 * HID,
        ln_g + i * HID, ln_b + i * HID, h, n);
  }

  gemm_tiled<HID, 1, true, false><<<dim3(mtiles, 1), 256, 0, stream>>>(
      h, HID, n, Wc1, Wc1, Wc1, Wc1, bc1, bc1, bc1, bc1, h1, HID, nullptr);
  cls2_kernel<<<(n + 255) / 256, 256, 0, stream>>>(h1, Wc2, bc2, out, n);
}